// Round 3
// baseline (922.686 us; speedup 1.0000x reference)
//
#include <hip/hip_runtime.h>
#include <stdint.h>
#include <math.h>

#define N_NODES  10000
#define N_EDGES  5000000
#define BATCH    2000
#define N_PAIRS  1999000   // BATCH*(BATCH-1)/2

// Output offsets (float32 elements), concatenated in reference return order
#define OUT_BN      0
#define OUT_PAIRS0  2000
#define OUT_PAIRS1  2001000
#define OUT_ES0     4000000
#define OUT_ES1     9000000
#define OUT_T       14000000
#define OUT_S       19000000
#define OUT_M       24000000

// Workspace layout (bytes)
#define WS_KEYS     0          // 10000 x u64
#define WS_SEL      80000      // 10000 x i32
#define WS_BN       120000     // 2000  x i32
#define WS_CNT      128000     // 10000 x i32   (zeroed)
#define WS_FILL     168000     // 10000 x i32   (zeroed)
#define WS_OFF      208000     // 10001 x i32
#define WS_SCRATCH  248008     // 5M x u64 (or 5M x u32 fallback)

// ---------------------------------------------------------------------------
// Gumbel score -> descending-sortable key with ascending-index tiebreak.
// Mirrors: u = max(tiny, bitcast(bits>>9 | 0x3f800000)-1 + tiny)  (f32 ops)
//          t1 = log_f32(u); g = -log_f32(-t1); score = log_f32(w) + g
// (f32 logs emulated by correctly-rounded double log -> float)
__device__ __forceinline__ unsigned long long score_key(int w, unsigned bits) {
  const float TINY = 1.17549435e-38f;
  float uf = __uint_as_float((bits >> 9) | 0x3f800000u) - 1.0f;
  float val = fmaxf(TINY, uf + TINY);
  float t1 = (float)log((double)val);            // inner log, rounded to f32
  float gmb = -(float)log((double)(-t1));        // outer log on f32-rounded input
  float score = (w > 0) ? ((float)log((double)w) + gmb) : (-INFINITY);
  unsigned fb = __float_as_uint(score);
  unsigned s = (fb & 0x80000000u) ? ~fb : (fb | 0x80000000u); // ascending order
  unsigned d = ~s;                                            // descending
  return ((unsigned long long)d << 32) | (unsigned)w;
}

// JAX threefry2x32, PARTITIONABLE mode (default in modern jax):
// counts1, counts2 = iota_2x32_shape(shape) = (hi, lo) of uint64 flat index
//   -> for n<2^32: (x0, x1) = (0, i) (+ key injection)
// bits1, bits2 = threefry2x32(k1, k2, counts1, counts2)
// bit_width 32 result = bits1 ^ bits2   <-- XOR of BOTH output words
__global__ void k_scores(unsigned long long* __restrict__ keys) {
  int v = blockIdx.x * blockDim.x + threadIdx.x;
  if (v >= N_NODES) return;
  unsigned ks[3] = {0u, 19u, 0u ^ 19u ^ 0x1BD11BDAu};
  unsigned x0 = 0u + ks[0];           // counter hi word (index < 2^32)
  unsigned x1 = (unsigned)v + ks[1];  // counter lo word
  const int R0[4] = {13, 15, 26, 6};
  const int R1[4] = {17, 29, 16, 24};
#pragma unroll
  for (int g = 0; g < 5; ++g) {
    const int* R = (g & 1) ? R1 : R0;
#pragma unroll
    for (int r = 0; r < 4; ++r) {
      x0 += x1;
      x1 = (x1 << R[r]) | (x1 >> (32 - R[r]));
      x1 ^= x0;
    }
    x0 += ks[(g + 1) % 3];
    x1 += ks[(g + 2) % 3] + (unsigned)(g + 1);
  }
  keys[v] = score_key(v, x0 ^ x1);
}

// Rank each node's key among all 10000 (unique keys); selected iff rank < 2000.
__global__ void k_rank(const unsigned long long* __restrict__ keys,
                       int* __restrict__ sel) {
  __shared__ unsigned long long lk[2048];
  int v = blockIdx.x * blockDim.x + threadIdx.x;
  unsigned long long kv = (v < N_NODES) ? keys[v] : 0xFFFFFFFFFFFFFFFFull;
  int cnt = 0;
  for (int base = 0; base < N_NODES; base += 2048) {
    int len = min(2048, N_NODES - base);
    for (int t = threadIdx.x; t < len; t += blockDim.x) lk[t] = keys[base + t];
    __syncthreads();
    for (int t = 0; t < len; ++t) cnt += (lk[t] < kv) ? 1 : 0;
    __syncthreads();
  }
  if (v < N_NODES) sel[v] = (cnt < BATCH) ? 1 : 0;
}

// Ordered compaction of selected flags -> batch_nodes (single wave, ballot scan)
__global__ void k_compact(const int* __restrict__ sel, int* __restrict__ bn,
                          float* __restrict__ outbn) {
  int lane = threadIdx.x;  // 64 threads
  int total = 0;
  for (int base = 0; base < N_NODES; base += 64) {
    int v = base + lane;
    int flag = (v < N_NODES) ? sel[v] : 0;
    unsigned long long m = __ballot(flag != 0);
    int pre = __popcll(m & ((1ull << lane) - 1ull));
    if (flag) {
      int pos = total + pre;
      bn[pos] = v;
      outbn[pos] = (float)v;
    }
    total += __popcll(m);
  }
}

// batch_pairs via inverse triangular index. S(ii) = ii*(B-1) - ii*(ii-1)/2
__global__ void k_pairs(const int* __restrict__ bn, float* __restrict__ out) {
  int p = blockIdx.x * blockDim.x + threadIdx.x;
  if (p >= N_PAIRS) return;
  double t = 2.0 * BATCH - 1.0;
  int ii = (int)((t - sqrt(t * t - 8.0 * (double)p)) * 0.5);
  if (ii < 0) ii = 0;
  if (ii > BATCH - 2) ii = BATCH - 2;
  while (ii > 0 &&
         (long long)ii * (BATCH - 1) - (long long)ii * (ii - 1) / 2 > p) --ii;
  while ((long long)(ii + 1) * (BATCH - 1) - (long long)(ii + 1) * ii / 2 <= p) ++ii;
  long long S = (long long)ii * (BATCH - 1) - (long long)ii * (ii - 1) / 2;
  int jj = ii + 1 + (int)(p - S);
  out[p] = (float)bn[ii];
  out[N_PAIRS + p] = (float)bn[jj];
}

// Row histogram over source node i (LDS-local, merged with global atomics)
__global__ void k_hist(const int* __restrict__ e_i, int* __restrict__ cnt) {
  __shared__ int h[N_NODES];
  for (int t = threadIdx.x; t < N_NODES; t += blockDim.x) h[t] = 0;
  __syncthreads();
  int stride = gridDim.x * blockDim.x;
  for (int e = blockIdx.x * blockDim.x + threadIdx.x; e < N_EDGES; e += stride)
    atomicAdd(&h[e_i[e]], 1);
  __syncthreads();
  for (int t = threadIdx.x; t < N_NODES; t += blockDim.x) {
    int c = h[t];
    if (c) atomicAdd(&cnt[t], c);
  }
}

// Exclusive scan of 10000 row counts (single block)
__global__ void k_scan(const int* __restrict__ cnt, int* __restrict__ off) {
  __shared__ int ls[1024];
  const int PER = 10;  // 1024*10 >= 10000
  int tid = threadIdx.x;
  int base = tid * PER;
  int s = 0;
  for (int k = 0; k < PER; ++k) {
    int i = base + k;
    if (i < N_NODES) s += cnt[i];
  }
  ls[tid] = s;
  __syncthreads();
  for (int d = 1; d < 1024; d <<= 1) {
    int val = (tid >= d) ? ls[tid - d] : 0;
    __syncthreads();
    ls[tid] += val;
    __syncthreads();
  }
  int run = (tid > 0) ? ls[tid - 1] : 0;
  for (int k = 0; k < PER; ++k) {
    int i = base + k;
    if (i < N_NODES) {
      off[i] = run;
      run += cnt[i];
    }
  }
  if (tid == 0) off[N_NODES] = N_EDGES;
}

// Scatter edges into row buckets (order within row arbitrary; fixed by sort)
__global__ void k_scatter(const int* __restrict__ e_i, const int* __restrict__ e_j,
                          const int* __restrict__ off, int* __restrict__ fill,
                          unsigned long long* __restrict__ sk64,
                          unsigned* __restrict__ sk32, int use64) {
  int stride = gridDim.x * blockDim.x;
  for (int e = blockIdx.x * blockDim.x + threadIdx.x; e < N_EDGES; e += stride) {
    int i = e_i[e];
    int slot = off[i] + atomicAdd(&fill[i], 1);
    if (use64)
      sk64[slot] = ((unsigned long long)(unsigned)e_j[e] << 32) | (unsigned)e;
    else
      sk32[slot] = (unsigned)e;
  }
}

// Per-row bitonic sort on key64=(j<<32)|idx (unique -> stable order by (j,idx)),
// then emit edges_sorted / batch_edge_times / batch_states / mask directly.
__global__ void __launch_bounds__(256) k_rowsort(
    const unsigned long long* __restrict__ sk64, const unsigned* __restrict__ sk32,
    int use64, const int* __restrict__ e_j_arr, const int* __restrict__ off,
    const float* __restrict__ times, const int* __restrict__ states,
    const int* __restrict__ sel, float* __restrict__ out) {
  __shared__ unsigned long long key[2048];
  int row = blockIdx.x;
  int o0 = off[row], o1 = off[row + 1];
  int len = o1 - o0;
  if (len <= 0) return;
  if (len > 2048) len = 2048;  // statistically impossible (69 sigma)
  int M = 2;
  while (M < len) M <<= 1;
  for (int t = threadIdx.x; t < M; t += blockDim.x) {
    if (t < len) {
      if (use64) {
        key[t] = sk64[o0 + t];
      } else {
        unsigned e = sk32[o0 + t];
        key[t] = ((unsigned long long)(unsigned)e_j_arr[e] << 32) | e;
      }
    } else {
      key[t] = 0xFFFFFFFFFFFFFFFFull;
    }
  }
  __syncthreads();
  for (int k = 2; k <= M; k <<= 1) {
    for (int j = k >> 1; j > 0; j >>= 1) {
      for (int t = threadIdx.x; t < M; t += blockDim.x) {
        int ixj = t ^ j;
        if (ixj > t) {
          unsigned long long a = key[t], b = key[ixj];
          bool up = ((t & k) == 0);
          if (up ? (a > b) : (a < b)) {
            key[t] = b;
            key[ixj] = a;
          }
        }
      }
      __syncthreads();
    }
  }
  int mi = sel[row];
  float frow = (float)row;
  for (int t = threadIdx.x; t < len; t += blockDim.x) {
    unsigned long long k = key[t];
    int j = (int)(k >> 32);
    int idx = (int)(k & 0xFFFFFFFFull);
    int p = o0 + t;
    out[OUT_ES0 + p] = frow;
    out[OUT_ES1 + p] = (float)j;
    bool m = (mi != 0) && (sel[j] != 0);
    float tm = times[idx];
    int st = states[idx];
    out[OUT_T + p] = m ? tm : 0.0f;
    out[OUT_S + p] = m ? (float)st : 0.0f;
    out[OUT_M + p] = m ? 1.0f : 0.0f;
  }
}

extern "C" void kernel_launch(void* const* d_in, const int* in_sizes, int n_in,
                              void* d_out, int out_size, void* d_ws, size_t ws_size,
                              hipStream_t stream) {
  const int* edges = (const int*)d_in[0];       // (2, E): [0..E)=i, [E..2E)=j
  const float* times = (const float*)d_in[1];
  const int* states = (const int*)d_in[2];
  const int* e_i = edges;
  const int* e_j = edges + N_EDGES;
  float* out = (float*)d_out;
  char* ws = (char*)d_ws;

  unsigned long long* keys = (unsigned long long*)(ws + WS_KEYS);
  int* sel = (int*)(ws + WS_SEL);
  int* bn = (int*)(ws + WS_BN);
  int* cnt = (int*)(ws + WS_CNT);
  int* fill = (int*)(ws + WS_FILL);
  int* off = (int*)(ws + WS_OFF);
  unsigned long long* sk64 = (unsigned long long*)(ws + WS_SCRATCH);
  unsigned* sk32 = (unsigned*)(ws + WS_SCRATCH);
  int use64 = (ws_size >= (size_t)WS_SCRATCH + 8ull * N_EDGES) ? 1 : 0;

  hipMemsetAsync(ws + WS_CNT, 0, 80000, stream);  // cnt + fill (contiguous)

  k_scores<<<(N_NODES + 255) / 256, 256, 0, stream>>>(keys);
  k_rank<<<(N_NODES + 255) / 256, 256, 0, stream>>>(keys, sel);
  k_compact<<<1, 64, 0, stream>>>(sel, bn, out + OUT_BN);
  k_pairs<<<(N_PAIRS + 255) / 256, 256, 0, stream>>>(bn, out + OUT_PAIRS0);
  k_hist<<<160, 256, 0, stream>>>(e_i, cnt);
  k_scan<<<1, 1024, 0, stream>>>(cnt, off);
  k_scatter<<<2560, 256, 0, stream>>>(e_i, e_j, off, fill, sk64, sk32, use64);
  k_rowsort<<<N_NODES, 256, 0, stream>>>(sk64, sk32, use64, e_j, off, times,
                                         states, sel, out);
}